// Round 6
// baseline (459.868 us; speedup 1.0000x reference)
//
#include <hip/hip_runtime.h>

// 2-layer LSTM (HID=10), B=2048, T=1024 main + F=64 future steps.
//
// Round 13: all-4-gates-per-lane (v4f), 4 elements/wave.
// r12 post-mortem: VALU exec cut 38% -> wall -3.5%, VALUBusy 73->47%. With
// 1 wave/SIMD the wall = VALU issue + EXPOSED latency (DS hops, trans chains).
// Fix the structure, not the op count:
//  - lane = e*16 + u (e=0..3 elements/wave, u=unit 0..15, valid<10). Each
//    lane holds ALL FOUR gate rows (i,f,g,o) of unit u as one v4f.
//  - gate exchange (swz16 + cndmask) ELIMINATED: c = a.f*c + a.i*a.g and
//    h = a.o*ctanh(c) are lane-local.
//  - bcast10 via ds_swizzle (and=0x10, or=j): broadcasts lane j within each
//    16-group independently -> 10 swizzles serve 4 elements (DS/elem halved).
//  - every wave instruction serves 4 elements: issue/elem ~200 -> ~90 cyc.
// Chain/step: dots -> act -> c-fma -> ctanh -> mul -> bcast10 (ONE DS hop).
// Math identical to r7/r12 (same prescaled constants: sigmoid via
// rcp(1+exp2(sK*z)), tanh via fma(-2,rcp(1+exp2(tK*z)),1), cell state
// carried as tK*c, g-act prescaled by tK). Zero LDS. 512 single-wave blocks.

#define NB 512
#define TMAIN 1024
#define HID 10

typedef float v4f __attribute__((ext_vector_type(4)));

#define PIN4(v) asm volatile("" : "+v"(v))
#define PIN(v)  asm volatile("" : "+v"(v))

__device__ __forceinline__ float rcp_(float v)  { return __builtin_amdgcn_rcpf(v); }
__device__ __forceinline__ float exp2_(float v) { return __builtin_amdgcn_exp2f(v); }
__device__ __forceinline__ v4f mk4(float a, float b, float c, float d) {
    v4f r; r.x = a; r.y = b; r.z = c; r.w = d; return r;
}
__device__ __forceinline__ v4f splat4(float s) { return mk4(s, s, s, s); }
__device__ __forceinline__ v4f pfma4(v4f a, v4f b, v4f c) { return __builtin_elementwise_fma(a, b, c); }

template<int J>
__device__ __forceinline__ float bc16(float v) {   // broadcast lane J within each 16-group
    // BitMode: new_lane[4:0] = (lane & 0x10) | J  (bit5 preserved by HW)
    return __int_as_float(__builtin_amdgcn_ds_swizzle(__float_as_int(v), (J << 5) | 0x10));
}
__device__ __forceinline__ void bcast10(float h, float* hb) {
    hb[0] = bc16<0>(h); hb[1] = bc16<1>(h); hb[2] = bc16<2>(h); hb[3] = bc16<3>(h);
    hb[4] = bc16<4>(h); hb[5] = bc16<5>(h); hb[6] = bc16<6>(h); hb[7] = bc16<7>(h);
    hb[8] = bc16<8>(h); hb[9] = bc16<9>(h);
}

__global__ __launch_bounds__(64)
__attribute__((amdgpu_waves_per_eu(1)))
void lstm2_kernel(
    const float* __restrict__ x,
    const float* __restrict__ Wih1, const float* __restrict__ Whh1,
    const float* __restrict__ bih1, const float* __restrict__ bhh1,
    const float* __restrict__ Wih2, const float* __restrict__ Whh2,
    const float* __restrict__ bih2, const float* __restrict__ bhh2,
    const float* __restrict__ Wlin, const float* __restrict__ blin,
    const int* __restrict__ futp,
    float* __restrict__ out)
{
    const int lane = threadIdx.x;
    const int e    = lane >> 4;          // element 0..3 within the wave
    const int u    = lane & 15;          // unit (valid < 10)
    const int ge   = blockIdx.x * 4 + e;
    const int F    = futp[0];
    const int OUTW = TMAIN + F;

    const bool uok = (u < HID);
    const int  uu  = uok ? u : 0;
    const int  Ri  = 0 * HID + uu;
    const int  Rf  = 1 * HID + uu;
    const int  Rg  = 2 * HID + uu;
    const int  Ro  = 3 * HID + uu;

    const float tK = 2.8853900817779268f;    //  2*log2(e)
    const float sK = -1.4426950408889634f;   // -log2(e)
    const float mu = uok ? 1.f : 0.f;
    const v4f aK4 = mk4(mu * sK, mu * sK, mu * tK, mu * sK);  // (i,f,g,o) prescale
    const v4f aA4 = mk4(0.f, 0.f, tK, 0.f);
    const v4f aB4 = mk4(1.f, 1.f, -2.f * tK, 1.f);

    // ---- per-lane weight rows: all 4 gates of unit u, prescaled ----
    v4f whh1q[10], wih2q[10], whh2q[10];
    float wl[10];
    #pragma unroll
    for (int j = 0; j < HID; ++j) {
        whh1q[j] = aK4 * mk4(Whh1[Ri*HID + j], Whh1[Rf*HID + j],
                             Whh1[Rg*HID + j], Whh1[Ro*HID + j]);
        wih2q[j] = aK4 * mk4(Wih2[Ri*HID + j], Wih2[Rf*HID + j],
                             Wih2[Rg*HID + j], Wih2[Ro*HID + j]);
        whh2q[j] = aK4 * mk4(Whh2[Ri*HID + j], Whh2[Rf*HID + j],
                             Whh2[Rg*HID + j], Whh2[Ro*HID + j]);
        wl[j]    = Wlin[j];
    }
    v4f b1q   = aK4 * mk4(bih1[Ri] + bhh1[Ri], bih1[Rf] + bhh1[Rf],
                          bih1[Rg] + bhh1[Rg], bih1[Ro] + bhh1[Ro]);
    v4f b2q   = aK4 * mk4(bih2[Ri] + bhh2[Ri], bih2[Rf] + bhh2[Rf],
                          bih2[Rg] + bhh2[Rg], bih2[Ro] + bhh2[Ro]);
    v4f wih1q = aK4 * mk4(Wih1[Ri], Wih1[Rf], Wih1[Rg], Wih1[Ro]);
    float bl = blin[0];

    #pragma unroll
    for (int j = 0; j < HID; ++j) { PIN4(whh1q[j]); PIN4(wih2q[j]); PIN4(whh2q[j]); PIN(wl[j]); }
    PIN4(b1q); PIN4(b2q); PIN4(wih1q); PIN(bl);

    auto act4 = [&](v4f p) -> v4f {              // (sigma,sigma,tK*tanh,sigma)
        v4f q;
        q.x = rcp_(1.0f + exp2_(p.x));
        q.y = rcp_(1.0f + exp2_(p.y));
        q.z = rcp_(1.0f + exp2_(p.z));
        q.w = rcp_(1.0f + exp2_(p.w));
        return pfma4(aB4, q, aA4);
    };
    auto ctanh_ = [&](float cs) -> float {       // tanh of (tK-scaled) cell state
        return fmaf(-2.0f, rcp_(1.0f + exp2_(cs)), 1.0f);
    };
    // gate math fully lane-local: update c, return new h
    auto cellup = [&](v4f pre, float& c) -> float {
        v4f a = act4(pre);
        c = fmaf(a.y, c, a.x * a.z);             // f*c + i*(tK-scaled tanh g)
        return a.w * ctanh_(c);                  // o * tanh(c)
    };

    // ---- state (per lane) ----
    float c1 = 0.f, c2 = 0.f;
    float h1b[10], h2b[10];                      // broadcast h (per 16-group)
    #pragma unroll
    for (int j = 0; j < HID; ++j) { h1b[j] = 0.f; h2b[j] = 0.f; }

    auto dot10q = [&](const v4f* w, const float* hb, v4f init) -> v4f {
        v4f P = pfma4(w[0], splat4(hb[0]), init);
        v4f Q = w[1] * splat4(hb[1]);
        #pragma unroll
        for (int j = 2; j < HID; j += 2) {
            P = pfma4(w[j],     splat4(hb[j]),     P);
            Q = pfma4(w[j + 1], splat4(hb[j + 1]), Q);
        }
        return P + Q;
    };
    auto head_ = [&]() -> float {                // y from h2 broadcast (all lanes)
        float Y = fmaf(wl[0], h2b[0], bl);
        float Z = wl[1] * h2b[1];
        #pragma unroll
        for (int j = 2; j < HID; j += 2) {
            Y = fmaf(wl[j],     h2b[j],     Y);
            Z = fmaf(wl[j + 1], h2b[j + 1], Z);
        }
        return Y + Z;
    };

    auto cell2head = [&]() -> float {            // cell2 from h1b/h2b, then y
        v4f U = dot10q(wih2q, h1b, b2q);
        v4f V = dot10q(whh2q, h2b, splat4(0.f));
        float h2n = cellup(U + V, c2);
        bcast10(h2n, h2b);
        return head_();
    };

    // Pipelined iteration: cell2(t) and cell1(t+1) as parallel chains,
    // both consuming h1b = h1(t) before it is overwritten.
    auto pipe_iter = [&](float xn) -> float {
        v4f U = dot10q(wih2q, h1b, b2q);
        v4f V = dot10q(whh2q, h2b, splat4(0.f));
        v4f A = dot10q(whh1q, h1b, pfma4(wih1q, splat4(xn), b1q));
        float h2n = cellup(U + V, c2);
        float h1n = cellup(A, c1);
        bcast10(h2n, h2b);
        bcast10(h1n, h1b);
        return head_();
    };

    auto fstep = [&](float yt) -> float {        // serial future step
        v4f A = dot10q(whh1q, h1b, pfma4(wih1q, splat4(yt), b1q));
        float h1n = cellup(A, c1);
        bcast10(h1n, h1b);
        return cell2head();
    };

    // ---- prologue: h1(0), c1(0) from x[0] ----
    const float4* xrow = (const float4*)(x + (size_t)ge * TMAIN);
    float4* orow = (float4*)(out + (size_t)ge * OUTW);   // OUTW=1088, 16B rows
    float4 xv = xrow[0];
    {
        v4f a1 = act4(pfma4(wih1q, splat4(xv.x), b1q));
        c1 = a1.x * a1.z;                                // c1_old == 0
        float h1n = a1.w * ctanh_(c1);
        bcast10(h1n, h1b);
    }

    // ---- main loop: 255 groups of 4 pipelined iterations ----
    #pragma unroll 1
    for (int t4 = 0; t4 < TMAIN / 4 - 1; ++t4) {
        float4 xn = xrow[t4 + 1];
        float y0 = pipe_iter(xv.y);
        float y1 = pipe_iter(xv.z);
        float y2 = pipe_iter(xv.w);
        float y3 = pipe_iter(xn.x);
        if (u == 0) orow[t4] = make_float4(y0, y1, y2, y3);
        xv = xn;
    }
    {
        float y0 = pipe_iter(xv.y);
        float y1 = pipe_iter(xv.z);
        float y2 = pipe_iter(xv.w);
        float y3 = cell2head();
        if (u == 0) orow[TMAIN / 4 - 1] = make_float4(y0, y1, y2, y3);
    }

    // ---- future loop: serial; y uniform within each 16-group ----
    float yprev = head_();
    int t = 0;
    #pragma unroll 1
    for (; t + 3 < F; t += 4) {
        float y0 = fstep(yprev);
        float y1 = fstep(y0);
        float y2 = fstep(y1);
        float y3 = fstep(y2);
        if (u == 0) orow[(TMAIN + t) / 4] = make_float4(y0, y1, y2, y3);
        yprev = y3;
    }
    #pragma unroll 1
    for (; t < F; ++t) {
        yprev = fstep(yprev);
        if (u == 0) out[(size_t)ge * OUTW + TMAIN + t] = yprev;
    }
}

extern "C" void kernel_launch(void* const* d_in, const int* in_sizes, int n_in,
                              void* d_out, int out_size, void* d_ws, size_t ws_size,
                              hipStream_t stream) {
    const float* x    = (const float*)d_in[0];
    const float* Wih1 = (const float*)d_in[1];
    const float* Whh1 = (const float*)d_in[2];
    const float* bih1 = (const float*)d_in[3];
    const float* bhh1 = (const float*)d_in[4];
    const float* Wih2 = (const float*)d_in[5];
    const float* Whh2 = (const float*)d_in[6];
    const float* bih2 = (const float*)d_in[7];
    const float* bhh2 = (const float*)d_in[8];
    const float* Wlin = (const float*)d_in[9];
    const float* blin = (const float*)d_in[10];
    const int*   futp = (const int*)d_in[11];
    float* out = (float*)d_out;

    lstm2_kernel<<<NB, 64, 0, stream>>>(x, Wih1, Whh1, bih1, bhh1,
                                        Wih2, Whh2, bih2, bhh2,
                                        Wlin, blin, futp, out);
}

// Round 9
// 332.838 us; speedup vs baseline: 1.3817x; 1.3817x over previous
//
#include <hip/hip_runtime.h>

// 2-layer LSTM (HID=10), B=2048, T=1024 main + F=64 future steps.
//
// Round 16: third attempt at the r14 wave-split (r14/r15 died to infra:
// "container failed twice", no pytest output; kernel audited for hang
// vectors - none: non-divergent barriers x65, statically bounded indices,
// HW-verified swizzles from r13). Risk trims vs r15: dropped the
// amdgpu_waves_per_eu hint. Design unchanged:
//  - 512 blocks x 128 threads = 1024 waves = every SIMD gets one wave
//    (r13 left half the machine dark at best-ever 244 cyc/elem).
//  - wave0: cell1 for 4 elems; after bcast10 also computes
//    U(t) = Wih2*h1(t)+b2 (same broadcast, no extra hop), ds_write_b128
//    to LDS ring (per-lane contiguous, conflict-free).
//  - wave1: one chunk (16 steps) behind; reads lane's U (ds_read_b128),
//    V = Whh2*h2, lane-local gate math, bcast10(h2), head. Future loop
//    solo on wave1 after one-shot (c1,h1) LDS handoff.
//  - __syncthreads once per 16-step chunk (65 total).
// Math bit-identical to r13 (same dot order/constants) -> absmax ~6.1e-5.

#define NB 512
#define TMAIN 1024
#define HID 10
#define KCH 16
#define NCH (TMAIN / KCH)   // 64 chunks

typedef float v4f __attribute__((ext_vector_type(4)));

#define PIN4(v) asm volatile("" : "+v"(v))
#define PIN(v)  asm volatile("" : "+v"(v))

__device__ __forceinline__ float rcp_(float v)  { return __builtin_amdgcn_rcpf(v); }
__device__ __forceinline__ float exp2_(float v) { return __builtin_amdgcn_exp2f(v); }
__device__ __forceinline__ v4f mk4(float a, float b, float c, float d) {
    v4f r; r.x = a; r.y = b; r.z = c; r.w = d; return r;
}
__device__ __forceinline__ v4f splat4(float s) { return mk4(s, s, s, s); }
__device__ __forceinline__ v4f pfma4(v4f a, v4f b, v4f c) { return __builtin_elementwise_fma(a, b, c); }

template<int J>
__device__ __forceinline__ float bc16(float v) {   // broadcast lane J within each 16-group
    return __int_as_float(__builtin_amdgcn_ds_swizzle(__float_as_int(v), (J << 5) | 0x10));
}
__device__ __forceinline__ void bcast10(float h, float* hb) {
    hb[0] = bc16<0>(h); hb[1] = bc16<1>(h); hb[2] = bc16<2>(h); hb[3] = bc16<3>(h);
    hb[4] = bc16<4>(h); hb[5] = bc16<5>(h); hb[6] = bc16<6>(h); hb[7] = bc16<7>(h);
    hb[8] = bc16<8>(h); hb[9] = bc16<9>(h);
}

__global__ __launch_bounds__(128)
void lstm2_kernel(
    const float* __restrict__ x,
    const float* __restrict__ Wih1, const float* __restrict__ Whh1,
    const float* __restrict__ bih1, const float* __restrict__ bhh1,
    const float* __restrict__ Wih2, const float* __restrict__ Whh2,
    const float* __restrict__ bih2, const float* __restrict__ bhh2,
    const float* __restrict__ Wlin, const float* __restrict__ blin,
    const int* __restrict__ futp,
    float* __restrict__ out)
{
    const int tid  = threadIdx.x;
    const int wid  = tid >> 6;           // 0 = cell1 producer, 1 = cell2+head consumer
    const int lane = tid & 63;
    const int e    = lane >> 4;          // element 0..3 within the wave
    const int u    = lane & 15;          // unit (valid < 10)
    const int ge   = blockIdx.x * 4 + e;
    const int F    = futp[0];
    const int OUTW = TMAIN + F;

    __shared__ v4f   ringU[2][KCH][64];  // U(t)=Wih2*h1(t)+b2 pre-acts, per lane
    __shared__ float stC[64], stH[64];   // final c1 / h1 handoff for future loop

    const bool uok = (u < HID);
    const int  uu  = uok ? u : 0;
    const int  Ri  = 0 * HID + uu;
    const int  Rf  = 1 * HID + uu;
    const int  Rg  = 2 * HID + uu;
    const int  Ro  = 3 * HID + uu;

    const float tK = 2.8853900817779268f;    //  2*log2(e)
    const float sK = -1.4426950408889634f;   // -log2(e)
    const float mu = uok ? 1.f : 0.f;
    const v4f aK4 = mk4(mu * sK, mu * sK, mu * tK, mu * sK);  // (i,f,g,o) prescale
    const v4f aA4 = mk4(0.f, 0.f, tK, 0.f);
    const v4f aB4 = mk4(1.f, 1.f, -2.f * tK, 1.f);

    // ---- per-lane weight rows (both waves load everything; future loop needs all) ----
    v4f whh1q[10], wih2q[10], whh2q[10];
    float wl[10];
    #pragma unroll
    for (int j = 0; j < HID; ++j) {
        whh1q[j] = aK4 * mk4(Whh1[Ri*HID + j], Whh1[Rf*HID + j],
                             Whh1[Rg*HID + j], Whh1[Ro*HID + j]);
        wih2q[j] = aK4 * mk4(Wih2[Ri*HID + j], Wih2[Rf*HID + j],
                             Wih2[Rg*HID + j], Wih2[Ro*HID + j]);
        whh2q[j] = aK4 * mk4(Whh2[Ri*HID + j], Whh2[Rf*HID + j],
                             Whh2[Rg*HID + j], Whh2[Ro*HID + j]);
        wl[j]    = Wlin[j];
    }
    v4f b1q   = aK4 * mk4(bih1[Ri] + bhh1[Ri], bih1[Rf] + bhh1[Rf],
                          bih1[Rg] + bhh1[Rg], bih1[Ro] + bhh1[Ro]);
    v4f b2q   = aK4 * mk4(bih2[Ri] + bhh2[Ri], bih2[Rf] + bhh2[Rf],
                          bih2[Rg] + bhh2[Rg], bih2[Ro] + bhh2[Ro]);
    v4f wih1q = aK4 * mk4(Wih1[Ri], Wih1[Rf], Wih1[Rg], Wih1[Ro]);
    float bl = blin[0];

    #pragma unroll
    for (int j = 0; j < HID; ++j) { PIN4(whh1q[j]); PIN4(wih2q[j]); PIN4(whh2q[j]); PIN(wl[j]); }
    PIN4(b1q); PIN4(b2q); PIN4(wih1q); PIN(bl);

    auto act4 = [&](v4f p) -> v4f {              // (sigma,sigma,tK*tanh,sigma)
        v4f q;
        q.x = rcp_(1.0f + exp2_(p.x));
        q.y = rcp_(1.0f + exp2_(p.y));
        q.z = rcp_(1.0f + exp2_(p.z));
        q.w = rcp_(1.0f + exp2_(p.w));
        return pfma4(aB4, q, aA4);
    };
    auto ctanh_ = [&](float cs) -> float {       // tanh of (tK-scaled) cell state
        return fmaf(-2.0f, rcp_(1.0f + exp2_(cs)), 1.0f);
    };
    auto cellup = [&](v4f pre, float& c) -> float {
        v4f a = act4(pre);
        c = fmaf(a.y, c, a.x * a.z);             // f*c + i*(tK-scaled tanh g)
        return a.w * ctanh_(c);                  // o * tanh(c)
    };
    auto dot10q = [&](const v4f* w, const float* hb, v4f init) -> v4f {
        v4f P = pfma4(w[0], splat4(hb[0]), init);
        v4f Q = w[1] * splat4(hb[1]);
        #pragma unroll
        for (int j = 2; j < HID; j += 2) {
            P = pfma4(w[j],     splat4(hb[j]),     P);
            Q = pfma4(w[j + 1], splat4(hb[j + 1]), Q);
        }
        return P + Q;
    };

    // ---- state ----
    float c1 = 0.f, c2 = 0.f, h1last = 0.f;
    float h1b[10], h2b[10];
    #pragma unroll
    for (int j = 0; j < HID; ++j) { h1b[j] = 0.f; h2b[j] = 0.f; }

    auto head_ = [&]() -> float {
        float Y = fmaf(wl[0], h2b[0], bl);
        float Z = wl[1] * h2b[1];
        #pragma unroll
        for (int j = 2; j < HID; j += 2) {
            Y = fmaf(wl[j],     h2b[j],     Y);
            Z = fmaf(wl[j + 1], h2b[j + 1], Z);
        }
        return Y + Z;
    };

    // producer step: cell1(t), broadcast h1(t), compute+stash U(t)
    auto pstep = [&](float xt, v4f* slot) {
        v4f A = dot10q(whh1q, h1b, pfma4(wih1q, splat4(xt), b1q));
        float h1n = cellup(A, c1);
        h1last = h1n;
        bcast10(h1n, h1b);
        v4f U = dot10q(wih2q, h1b, b2q);
        slot[lane] = U;
    };
    // consumer step: cell2(t) from preloaded U, then y(t)
    auto cstep = [&](v4f U) -> float {
        v4f V = dot10q(whh2q, h2b, splat4(0.f));
        float h2n = cellup(U + V, c2);
        bcast10(h2n, h2b);
        return head_();
    };
    // serial future step (wave1): cell1 then cell2
    auto fstep = [&](float yt) -> float {
        v4f A = dot10q(whh1q, h1b, pfma4(wih1q, splat4(yt), b1q));
        float h1n = cellup(A, c1);
        bcast10(h1n, h1b);
        v4f U = dot10q(wih2q, h1b, b2q);
        return cstep(U);
    };

    const float4* xrow = (const float4*)(x + (size_t)ge * TMAIN);
    float4* orow = (float4*)(out + (size_t)ge * OUTW);   // OUTW=1088, 16B rows

    // producer x prefetch: chunk 0 loaded before the loop
    float4 xq0 = make_float4(0.f, 0.f, 0.f, 0.f);
    float4 xq1 = xq0, xq2 = xq0, xq3 = xq0;
    if (wid == 0) { xq0 = xrow[0]; xq1 = xrow[1]; xq2 = xrow[2]; xq3 = xrow[3]; }

    float yprev = 0.f;

    // ---- main pipeline: 65 chunk-iterations, consumer one chunk behind ----
    #pragma unroll 1
    for (int c = 0; c <= NCH; ++c) {
        if (wid == 0) {
            if (c < NCH) {
                // prefetch next chunk's x while computing this one
                float4 xn0 = make_float4(0.f, 0.f, 0.f, 0.f);
                float4 xn1 = xn0, xn2 = xn0, xn3 = xn0;
                if (c + 1 < NCH) {
                    xn0 = xrow[(c+1)*4+0]; xn1 = xrow[(c+1)*4+1];
                    xn2 = xrow[(c+1)*4+2]; xn3 = xrow[(c+1)*4+3];
                }
                v4f* rb = &ringU[c & 1][0][0];
                pstep(xq0.x, rb + 0*64);  pstep(xq0.y, rb + 1*64);
                pstep(xq0.z, rb + 2*64);  pstep(xq0.w, rb + 3*64);
                pstep(xq1.x, rb + 4*64);  pstep(xq1.y, rb + 5*64);
                pstep(xq1.z, rb + 6*64);  pstep(xq1.w, rb + 7*64);
                pstep(xq2.x, rb + 8*64);  pstep(xq2.y, rb + 9*64);
                pstep(xq2.z, rb + 10*64); pstep(xq2.w, rb + 11*64);
                pstep(xq3.x, rb + 12*64); pstep(xq3.y, rb + 13*64);
                pstep(xq3.z, rb + 14*64); pstep(xq3.w, rb + 15*64);
                if (c == NCH - 1) { stC[lane] = c1; stH[lane] = h1last; }
                xq0 = xn0; xq1 = xn1; xq2 = xn2; xq3 = xn3;
            }
        } else {
            if (c >= 1) {
                const v4f* rb = &ringU[(c - 1) & 1][0][0];
                #pragma unroll
                for (int q = 0; q < 4; ++q) {
                    v4f U0 = rb[(q*4 + 0)*64 + lane];
                    v4f U1 = rb[(q*4 + 1)*64 + lane];
                    v4f U2 = rb[(q*4 + 2)*64 + lane];
                    v4f U3 = rb[(q*4 + 3)*64 + lane];
                    float y0 = cstep(U0);
                    float y1 = cstep(U1);
                    float y2 = cstep(U2);
                    float y3 = cstep(U3);
                    if (u == 0) orow[(c - 1)*4 + q] = make_float4(y0, y1, y2, y3);
                    yprev = y3;
                }
            }
        }
        __syncthreads();
    }

    // ---- future loop: wave1 only, fully serial (y feeds back) ----
    if (wid == 1) {
        c1 = stC[lane];
        bcast10(stH[lane], h1b);
        float yp = yprev;
        int t = 0;
        #pragma unroll 1
        for (; t + 3 < F; t += 4) {
            float y0 = fstep(yp);
            float y1 = fstep(y0);
            float y2 = fstep(y1);
            float y3 = fstep(y2);
            if (u == 0) orow[(TMAIN + t) / 4] = make_float4(y0, y1, y2, y3);
            yp = y3;
        }
        #pragma unroll 1
        for (; t < F; ++t) {
            yp = fstep(yp);
            if (u == 0) out[(size_t)ge * OUTW + TMAIN + t] = yp;
        }
    }
}

extern "C" void kernel_launch(void* const* d_in, const int* in_sizes, int n_in,
                              void* d_out, int out_size, void* d_ws, size_t ws_size,
                              hipStream_t stream) {
    const float* x    = (const float*)d_in[0];
    const float* Wih1 = (const float*)d_in[1];
    const float* Whh1 = (const float*)d_in[2];
    const float* bih1 = (const float*)d_in[3];
    const float* bhh1 = (const float*)d_in[4];
    const float* Wih2 = (const float*)d_in[5];
    const float* Whh2 = (const float*)d_in[6];
    const float* bih2 = (const float*)d_in[7];
    const float* bhh2 = (const float*)d_in[8];
    const float* Wlin = (const float*)d_in[9];
    const float* blin = (const float*)d_in[10];
    const int*   futp = (const int*)d_in[11];
    float* out = (float*)d_out;

    lstm2_kernel<<<NB, 128, 0, stream>>>(x, Wih1, Whh1, bih1, bhh1,
                                         Wih2, Whh2, bih2, bhh2,
                                         Wlin, blin, futp, out);
}

// Round 10
// 331.685 us; speedup vs baseline: 1.3865x; 1.0035x over previous
//
#include <hip/hip_runtime.h>

// 2-layer LSTM (HID=10), B=2048, T=1024 main + F=64 future steps.
//
// Round 17: guaranteed-pk arithmetic on the r16 wave-split structure.
// r16 (283us steady, passed): VALUBusy 50% = ~314 busy cyc/SIMD/step, but
// the instruction audit gives ~75 ops IF v4f lowered to v_pk_fma_f32 and
// ~135 if scalar -> the busy-cycle arithmetic says v4f lowers (near-)scalar.
// r7 (prior session) VERIFIED v2f + __builtin_elementwise_fma emits
// v_pk_fma_f32. So: keep r16's proven structure (512 blocks x 128 thr,
// producer wave0 = cell1+U-stash, consumer wave1 = cell2+head one 16-step
// chunk behind, LDS ringU, one barrier/chunk, (c1,h1) handoff), and rewrite
// ONLY the math in explicit v2f pairs:
//  - gates split (i,f)/(g,o); dots = 20 pk_fma + 2 pk_add with the same
//    P(even)/Q(odd) accumulation order -> bit-identical results.
//  - act: 4 exp2 + 4 rcp + 2 pk_add + 1 fma; cell update scalar.
//  - head: 5 pk_fma over (even,odd) j-pairs + 1 horizontal add, exactly
//    reproducing r16's Y/Z chains.
// Predicted: issue/SIMD/step 314 -> ~190, dur 283 -> ~225-250, absmax
// exactly 6.103516e-05. Falsification: <5% delta => v4f was already pk.

#define NB 512
#define TMAIN 1024
#define HID 10
#define KCH 16
#define NCH (TMAIN / KCH)   // 64 chunks

typedef float v2f __attribute__((ext_vector_type(2)));
typedef float v4f __attribute__((ext_vector_type(4)));

#define PIN2(v) asm volatile("" : "+v"(v))
#define PIN(v)  asm volatile("" : "+v"(v))

__device__ __forceinline__ float rcp_(float v)  { return __builtin_amdgcn_rcpf(v); }
__device__ __forceinline__ float exp2_(float v) { return __builtin_amdgcn_exp2f(v); }
__device__ __forceinline__ v2f mk2(float x, float y) { v2f r; r.x = x; r.y = y; return r; }
__device__ __forceinline__ v2f pfma2(v2f a, v2f b, v2f c) { return __builtin_elementwise_fma(a, b, c); }

template<int J>
__device__ __forceinline__ float bc16(float v) {   // broadcast lane J within each 16-group
    return __int_as_float(__builtin_amdgcn_ds_swizzle(__float_as_int(v), (J << 5) | 0x10));
}
__device__ __forceinline__ void bcast10(float h, float* hb) {
    hb[0] = bc16<0>(h); hb[1] = bc16<1>(h); hb[2] = bc16<2>(h); hb[3] = bc16<3>(h);
    hb[4] = bc16<4>(h); hb[5] = bc16<5>(h); hb[6] = bc16<6>(h); hb[7] = bc16<7>(h);
    hb[8] = bc16<8>(h); hb[9] = bc16<9>(h);
}

__global__ __launch_bounds__(128)
void lstm2_kernel(
    const float* __restrict__ x,
    const float* __restrict__ Wih1, const float* __restrict__ Whh1,
    const float* __restrict__ bih1, const float* __restrict__ bhh1,
    const float* __restrict__ Wih2, const float* __restrict__ Whh2,
    const float* __restrict__ bih2, const float* __restrict__ bhh2,
    const float* __restrict__ Wlin, const float* __restrict__ blin,
    const int* __restrict__ futp,
    float* __restrict__ out)
{
    const int tid  = threadIdx.x;
    const int wid  = tid >> 6;           // 0 = cell1 producer, 1 = cell2+head consumer
    const int lane = tid & 63;
    const int e    = lane >> 4;          // element 0..3 within the wave
    const int u    = lane & 15;          // unit (valid < 10)
    const int ge   = blockIdx.x * 4 + e;
    const int F    = futp[0];
    const int OUTW = TMAIN + F;

    __shared__ v4f   ringU[2][KCH][64];  // U(t)=Wih2*h1(t)+b2 pre-acts (i,f,g,o)
    __shared__ float stC[64], stH[64];   // final c1 / h1 handoff for future loop

    const bool uok = (u < HID);
    const int  uu  = uok ? u : 0;
    const int  Ri  = 0 * HID + uu;
    const int  Rf  = 1 * HID + uu;
    const int  Rg  = 2 * HID + uu;
    const int  Ro  = 3 * HID + uu;

    const float tK = 2.8853900817779268f;    //  2*log2(e)
    const float sK = -1.4426950408889634f;   // -log2(e)
    const float mu = uok ? 1.f : 0.f;
    const float sKm = mu * sK;               // sigmoid prescale (i,f,o)
    const float tKm = mu * tK;               // tanh prescale (g)

    // ---- per-lane weight rows split into (i,f) / (g,o) v2f pairs, prescaled ----
    v2f w1_if[10], w1_go[10], w2i_if[10], w2i_go[10], w2h_if[10], w2h_go[10];
    v2f wlp[5];
    #pragma unroll
    for (int j = 0; j < HID; ++j) {
        w1_if[j]  = mk2(sKm * Whh1[Ri*HID + j], sKm * Whh1[Rf*HID + j]);
        w1_go[j]  = mk2(tKm * Whh1[Rg*HID + j], sKm * Whh1[Ro*HID + j]);
        w2i_if[j] = mk2(sKm * Wih2[Ri*HID + j], sKm * Wih2[Rf*HID + j]);
        w2i_go[j] = mk2(tKm * Wih2[Rg*HID + j], sKm * Wih2[Ro*HID + j]);
        w2h_if[j] = mk2(sKm * Whh2[Ri*HID + j], sKm * Whh2[Rf*HID + j]);
        w2h_go[j] = mk2(tKm * Whh2[Rg*HID + j], sKm * Whh2[Ro*HID + j]);
    }
    #pragma unroll
    for (int k = 0; k < 5; ++k) wlp[k] = mk2(Wlin[2*k], Wlin[2*k + 1]);
    v2f b1_if = mk2(sKm * (bih1[Ri] + bhh1[Ri]), sKm * (bih1[Rf] + bhh1[Rf]));
    v2f b1_go = mk2(tKm * (bih1[Rg] + bhh1[Rg]), sKm * (bih1[Ro] + bhh1[Ro]));
    v2f b2_if = mk2(sKm * (bih2[Ri] + bhh2[Ri]), sKm * (bih2[Rf] + bhh2[Rf]));
    v2f b2_go = mk2(tKm * (bih2[Rg] + bhh2[Rg]), sKm * (bih2[Ro] + bhh2[Ro]));
    v2f wx_if = mk2(sKm * Wih1[Ri], sKm * Wih1[Rf]);
    v2f wx_go = mk2(tKm * Wih1[Rg], sKm * Wih1[Ro]);
    float bl = blin[0];

    #pragma unroll
    for (int j = 0; j < HID; ++j) {
        PIN2(w1_if[j]); PIN2(w1_go[j]); PIN2(w2i_if[j]); PIN2(w2i_go[j]);
        PIN2(w2h_if[j]); PIN2(w2h_go[j]);
    }
    #pragma unroll
    for (int k = 0; k < 5; ++k) PIN2(wlp[k]);
    PIN2(b1_if); PIN2(b1_go); PIN2(b2_if); PIN2(b2_go); PIN2(wx_if); PIN2(wx_go); PIN(bl);

    auto ctanh_ = [&](float cs) -> float {       // tanh of (tK-scaled) cell state
        return fmaf(-2.0f, rcp_(1.0f + exp2_(cs)), 1.0f);
    };
    // gate math (bit-identical to r16's act4+cellup): p pairs -> update c, return h
    auto cellup2 = [&](v2f p_if, v2f p_go, float& c) -> float {
        v2f q_if, q_go;
        q_if.x = rcp_(1.0f + exp2_(p_if.x));     // i
        q_if.y = rcp_(1.0f + exp2_(p_if.y));     // f
        q_go.x = rcp_(1.0f + exp2_(p_go.x));     // g (pre-act)
        q_go.y = rcp_(1.0f + exp2_(p_go.y));     // o
        float g = fmaf(-2.0f * tK, q_go.x, tK);  // tK*tanh
        c = fmaf(q_if.y, c, q_if.x * g);         // f*c + i*g
        return q_go.y * ctanh_(c);               // o * tanh(c)
    };
    // P(even)/Q(odd) pk dot over 10 broadcast scalars -> (lo,hi) gate pair
    auto dotp = [&](const v2f* w, const float* hb, v2f init) -> v2f {
        v2f P = pfma2(w[0], mk2(hb[0], hb[0]), init);
        v2f Q = w[1] * mk2(hb[1], hb[1]);
        #pragma unroll
        for (int j = 2; j < HID; j += 2) {
            P = pfma2(w[j],     mk2(hb[j],     hb[j]),     P);
            Q = pfma2(w[j + 1], mk2(hb[j + 1], hb[j + 1]), Q);
        }
        return P + Q;
    };

    // ---- state ----
    float c1 = 0.f, c2 = 0.f, h1last = 0.f;
    float h1b[10], h2b[10];
    #pragma unroll
    for (int j = 0; j < HID; ++j) { h1b[j] = 0.f; h2b[j] = 0.f; }

    auto head_ = [&]() -> float {                // exactly r16's Y/Z chains
        v2f Y = pfma2(wlp[0], mk2(h2b[0], h2b[1]), mk2(bl, 0.f));
        #pragma unroll
        for (int k = 1; k < 5; ++k)
            Y = pfma2(wlp[k], mk2(h2b[2*k], h2b[2*k + 1]), Y);
        return Y.x + Y.y;
    };

    // producer step: cell1(t), broadcast h1(t), compute+stash U(t)
    auto pstep = [&](float xt, v4f* slot) {
        v2f A_if = dotp(w1_if, h1b, pfma2(wx_if, mk2(xt, xt), b1_if));
        v2f A_go = dotp(w1_go, h1b, pfma2(wx_go, mk2(xt, xt), b1_go));
        float h1n = cellup2(A_if, A_go, c1);
        h1last = h1n;
        bcast10(h1n, h1b);
        v2f U_if = dotp(w2i_if, h1b, b2_if);
        v2f U_go = dotp(w2i_go, h1b, b2_go);
        v4f U; U.x = U_if.x; U.y = U_if.y; U.z = U_go.x; U.w = U_go.y;
        slot[lane] = U;
    };
    // consumer step: cell2(t) from preloaded U, then y(t)
    auto cstep = [&](v4f U) -> float {
        v2f V_if = dotp(w2h_if, h2b, mk2(U.x, U.y));
        v2f V_go = dotp(w2h_go, h2b, mk2(U.z, U.w));
        float h2n = cellup2(V_if, V_go, c2);
        bcast10(h2n, h2b);
        return head_();
    };
    // serial future step (wave1): cell1 then cell2
    auto fstep = [&](float yt) -> float {
        v2f A_if = dotp(w1_if, h1b, pfma2(wx_if, mk2(yt, yt), b1_if));
        v2f A_go = dotp(w1_go, h1b, pfma2(wx_go, mk2(yt, yt), b1_go));
        float h1n = cellup2(A_if, A_go, c1);
        bcast10(h1n, h1b);
        v2f U_if = dotp(w2i_if, h1b, b2_if);
        v2f U_go = dotp(w2i_go, h1b, b2_go);
        v4f U; U.x = U_if.x; U.y = U_if.y; U.z = U_go.x; U.w = U_go.y;
        return cstep(U);
    };

    const float4* xrow = (const float4*)(x + (size_t)ge * TMAIN);
    float4* orow = (float4*)(out + (size_t)ge * OUTW);   // OUTW=1088, 16B rows

    // producer x prefetch: chunk 0 loaded before the loop
    float4 xq0 = make_float4(0.f, 0.f, 0.f, 0.f);
    float4 xq1 = xq0, xq2 = xq0, xq3 = xq0;
    if (wid == 0) { xq0 = xrow[0]; xq1 = xrow[1]; xq2 = xrow[2]; xq3 = xrow[3]; }

    float yprev = 0.f;

    // ---- main pipeline: 65 chunk-iterations, consumer one chunk behind ----
    #pragma unroll 1
    for (int c = 0; c <= NCH; ++c) {
        if (wid == 0) {
            if (c < NCH) {
                float4 xn0 = make_float4(0.f, 0.f, 0.f, 0.f);
                float4 xn1 = xn0, xn2 = xn0, xn3 = xn0;
                if (c + 1 < NCH) {
                    xn0 = xrow[(c+1)*4+0]; xn1 = xrow[(c+1)*4+1];
                    xn2 = xrow[(c+1)*4+2]; xn3 = xrow[(c+1)*4+3];
                }
                v4f* rb = &ringU[c & 1][0][0];
                pstep(xq0.x, rb + 0*64);  pstep(xq0.y, rb + 1*64);
                pstep(xq0.z, rb + 2*64);  pstep(xq0.w, rb + 3*64);
                pstep(xq1.x, rb + 4*64);  pstep(xq1.y, rb + 5*64);
                pstep(xq1.z, rb + 6*64);  pstep(xq1.w, rb + 7*64);
                pstep(xq2.x, rb + 8*64);  pstep(xq2.y, rb + 9*64);
                pstep(xq2.z, rb + 10*64); pstep(xq2.w, rb + 11*64);
                pstep(xq3.x, rb + 12*64); pstep(xq3.y, rb + 13*64);
                pstep(xq3.z, rb + 14*64); pstep(xq3.w, rb + 15*64);
                if (c == NCH - 1) { stC[lane] = c1; stH[lane] = h1last; }
                xq0 = xn0; xq1 = xn1; xq2 = xn2; xq3 = xn3;
            }
        } else {
            if (c >= 1) {
                const v4f* rb = &ringU[(c - 1) & 1][0][0];
                #pragma unroll
                for (int q = 0; q < 4; ++q) {
                    v4f U0 = rb[(q*4 + 0)*64 + lane];
                    v4f U1 = rb[(q*4 + 1)*64 + lane];
                    v4f U2 = rb[(q*4 + 2)*64 + lane];
                    v4f U3 = rb[(q*4 + 3)*64 + lane];
                    float y0 = cstep(U0);
                    float y1 = cstep(U1);
                    float y2 = cstep(U2);
                    float y3 = cstep(U3);
                    if (u == 0) orow[(c - 1)*4 + q] = make_float4(y0, y1, y2, y3);
                    yprev = y3;
                }
            }
        }
        __syncthreads();
    }

    // ---- future loop: wave1 only, fully serial (y feeds back) ----
    if (wid == 1) {
        c1 = stC[lane];
        bcast10(stH[lane], h1b);
        float yp = yprev;
        int t = 0;
        #pragma unroll 1
        for (; t + 3 < F; t += 4) {
            float y0 = fstep(yp);
            float y1 = fstep(y0);
            float y2 = fstep(y1);
            float y3 = fstep(y2);
            if (u == 0) orow[(TMAIN + t) / 4] = make_float4(y0, y1, y2, y3);
            yp = y3;
        }
        #pragma unroll 1
        for (; t < F; ++t) {
            yp = fstep(yp);
            if (u == 0) out[(size_t)ge * OUTW + TMAIN + t] = yp;
        }
    }
}

extern "C" void kernel_launch(void* const* d_in, const int* in_sizes, int n_in,
                              void* d_out, int out_size, void* d_ws, size_t ws_size,
                              hipStream_t stream) {
    const float* x    = (const float*)d_in[0];
    const float* Wih1 = (const float*)d_in[1];
    const float* Whh1 = (const float*)d_in[2];
    const float* bih1 = (const float*)d_in[3];
    const float* bhh1 = (const float*)d_in[4];
    const float* Wih2 = (const float*)d_in[5];
    const float* Whh2 = (const float*)d_in[6];
    const float* bih2 = (const float*)d_in[7];
    const float* bhh2 = (const float*)d_in[8];
    const float* Wlin = (const float*)d_in[9];
    const float* blin = (const float*)d_in[10];
    const int*   futp = (const int*)d_in[11];
    float* out = (float*)d_out;

    lstm2_kernel<<<NB, 128, 0, stream>>>(x, Wih1, Whh1, bih1, bhh1,
                                         Wih2, Whh2, bih2, bhh2,
                                         Wlin, blin, futp, out);
}

// Round 11
// 324.204 us; speedup vs baseline: 1.4185x; 1.0231x over previous
//
#include <hip/hip_runtime.h>

// 2-layer LSTM (HID=10), B=2048, T=1024 main + F=64 future steps.
//
// Round 18: 4-role wave pipeline. r17 post-mortem: <2% delta from guaranteed-pk
// math (below the pre-committed 5% threshold) -> issue-content floor of the
// 2-wave split. Counters: VALUBusy 48% @ 1 wave/SIMD, wall 630 cyc/step vs
// ~300 busy -> ~330 cyc of dep-chain bubbles a lone wave can't fill. Adding
// waves only helps if per-wave streams SHRINK (r8: 2x full streams failed).
// So split each 4-elem stream over 4 waves (512 blocks x 256 thr = 2048 waves
// = 2/SIMD; HW round-robin puts 2 SAME-role waves per SIMD):
//  W0 cell1 (serial ~170 busy) -> h1 lanes to ringH1
//  W1 U = Wih2*h1+b2 (steps independent, light)  -> ringU
//  W2 cell2 (serial ~170 busy, reads U)          -> h2 lanes to ringH2
//  W3 head + y store (light); runs future loop after (c1,h1,c2,h2) handoff.
// Rings depth-2, chunk-skew 1/2/3, ONE barrier per chunk-iteration (67 total);
// no cross-wave hop sits inside either serial recurrence (bcast10 keeps each
// cell's h-loop wave-local). Gate math verbatim r17 -> bit-identical output.
// Predicted: two interleaved 170-cyc serial streams per cell-SIMD -> util
// ~85-90%, wall ~390-450 cyc/step, dur 277 -> ~180-220 us.

#define NB 512
#define TMAIN 1024
#define HID 10
#define KCH 16
#define NCH (TMAIN / KCH)   // 64 chunks

typedef float v2f __attribute__((ext_vector_type(2)));
typedef float v4f __attribute__((ext_vector_type(4)));

#define PIN2(v) asm volatile("" : "+v"(v))
#define PIN(v)  asm volatile("" : "+v"(v))

__device__ __forceinline__ float rcp_(float v)  { return __builtin_amdgcn_rcpf(v); }
__device__ __forceinline__ float exp2_(float v) { return __builtin_amdgcn_exp2f(v); }
__device__ __forceinline__ v2f mk2(float x, float y) { v2f r; r.x = x; r.y = y; return r; }
__device__ __forceinline__ v2f pfma2(v2f a, v2f b, v2f c) { return __builtin_elementwise_fma(a, b, c); }

template<int J>
__device__ __forceinline__ float bc16(float v) {   // broadcast lane J within each 16-group
    return __int_as_float(__builtin_amdgcn_ds_swizzle(__float_as_int(v), (J << 5) | 0x10));
}
__device__ __forceinline__ void bcast10(float h, float* hb) {
    hb[0] = bc16<0>(h); hb[1] = bc16<1>(h); hb[2] = bc16<2>(h); hb[3] = bc16<3>(h);
    hb[4] = bc16<4>(h); hb[5] = bc16<5>(h); hb[6] = bc16<6>(h); hb[7] = bc16<7>(h);
    hb[8] = bc16<8>(h); hb[9] = bc16<9>(h);
}

__global__ __launch_bounds__(256)
void lstm2_kernel(
    const float* __restrict__ x,
    const float* __restrict__ Wih1, const float* __restrict__ Whh1,
    const float* __restrict__ bih1, const float* __restrict__ bhh1,
    const float* __restrict__ Wih2, const float* __restrict__ Whh2,
    const float* __restrict__ bih2, const float* __restrict__ bhh2,
    const float* __restrict__ Wlin, const float* __restrict__ blin,
    const int* __restrict__ futp,
    float* __restrict__ out)
{
    const int tid  = threadIdx.x;
    const int wid  = tid >> 6;           // role: 0=cell1 1=U 2=cell2 3=head
    const int lane = tid & 63;
    const int e    = lane >> 4;          // element 0..3
    const int u    = lane & 15;          // unit (valid < 10)
    const int ge   = blockIdx.x * 4 + e;
    const int F    = futp[0];
    const int OUTW = TMAIN + F;

    __shared__ __align__(16) float ringH1[2][KCH][64];  // h1(t) lanes
    __shared__ __align__(16) v4f   ringU [2][KCH][64];  // U(t) pre-acts
    __shared__ __align__(16) float ringH2[2][KCH][64];  // h2(t) lanes
    __shared__ __align__(16) float stC1[64], stH1[64], stC2[64], stH2[64];

    const bool uok = (u < HID);
    const int  uu  = uok ? u : 0;
    const int  Ri  = 0 * HID + uu;
    const int  Rf  = 1 * HID + uu;
    const int  Rg  = 2 * HID + uu;
    const int  Ro  = 3 * HID + uu;

    const float tK = 2.8853900817779268f;    //  2*log2(e)
    const float sK = -1.4426950408889634f;   // -log2(e)
    const float mu = uok ? 1.f : 0.f;
    const float sKm = mu * sK;
    const float tKm = mu * tK;

    // ---- per-lane weights, (i,f)/(g,o) v2f pairs, prescaled (all waves) ----
    v2f w1_if[10], w1_go[10], w2i_if[10], w2i_go[10], w2h_if[10], w2h_go[10];
    v2f wlp[5];
    #pragma unroll
    for (int j = 0; j < HID; ++j) {
        w1_if[j]  = mk2(sKm * Whh1[Ri*HID + j], sKm * Whh1[Rf*HID + j]);
        w1_go[j]  = mk2(tKm * Whh1[Rg*HID + j], sKm * Whh1[Ro*HID + j]);
        w2i_if[j] = mk2(sKm * Wih2[Ri*HID + j], sKm * Wih2[Rf*HID + j]);
        w2i_go[j] = mk2(tKm * Wih2[Rg*HID + j], sKm * Wih2[Ro*HID + j]);
        w2h_if[j] = mk2(sKm * Whh2[Ri*HID + j], sKm * Whh2[Rf*HID + j]);
        w2h_go[j] = mk2(tKm * Whh2[Rg*HID + j], sKm * Whh2[Ro*HID + j]);
    }
    #pragma unroll
    for (int k = 0; k < 5; ++k) wlp[k] = mk2(Wlin[2*k], Wlin[2*k + 1]);
    v2f b1_if = mk2(sKm * (bih1[Ri] + bhh1[Ri]), sKm * (bih1[Rf] + bhh1[Rf]));
    v2f b1_go = mk2(tKm * (bih1[Rg] + bhh1[Rg]), sKm * (bih1[Ro] + bhh1[Ro]));
    v2f b2_if = mk2(sKm * (bih2[Ri] + bhh2[Ri]), sKm * (bih2[Rf] + bhh2[Rf]));
    v2f b2_go = mk2(tKm * (bih2[Rg] + bhh2[Rg]), sKm * (bih2[Ro] + bhh2[Ro]));
    v2f wx_if = mk2(sKm * Wih1[Ri], sKm * Wih1[Rf]);
    v2f wx_go = mk2(tKm * Wih1[Rg], sKm * Wih1[Ro]);
    float bl = blin[0];

    #pragma unroll
    for (int j = 0; j < HID; ++j) {
        PIN2(w1_if[j]); PIN2(w1_go[j]); PIN2(w2i_if[j]); PIN2(w2i_go[j]);
        PIN2(w2h_if[j]); PIN2(w2h_go[j]);
    }
    #pragma unroll
    for (int k = 0; k < 5; ++k) PIN2(wlp[k]);
    PIN2(b1_if); PIN2(b1_go); PIN2(b2_if); PIN2(b2_go); PIN2(wx_if); PIN2(wx_go); PIN(bl);

    auto ctanh_ = [&](float cs) -> float {
        return fmaf(-2.0f, rcp_(1.0f + exp2_(cs)), 1.0f);
    };
    auto cellup2 = [&](v2f p_if, v2f p_go, float& c) -> float {   // verbatim r17
        v2f q_if, q_go;
        q_if.x = rcp_(1.0f + exp2_(p_if.x));
        q_if.y = rcp_(1.0f + exp2_(p_if.y));
        q_go.x = rcp_(1.0f + exp2_(p_go.x));
        q_go.y = rcp_(1.0f + exp2_(p_go.y));
        float g = fmaf(-2.0f * tK, q_go.x, tK);
        c = fmaf(q_if.y, c, q_if.x * g);
        return q_go.y * ctanh_(c);
    };
    auto dotp = [&](const v2f* w, const float* hb, v2f init) -> v2f {  // verbatim r17
        v2f P = pfma2(w[0], mk2(hb[0], hb[0]), init);
        v2f Q = w[1] * mk2(hb[1], hb[1]);
        #pragma unroll
        for (int j = 2; j < HID; j += 2) {
            P = pfma2(w[j],     mk2(hb[j],     hb[j]),     P);
            Q = pfma2(w[j + 1], mk2(hb[j + 1], hb[j + 1]), Q);
        }
        return P + Q;
    };
    // uniform-address broadcast load of 10 floats (per 16-group base)
    auto loadhb = [&](const float* base, float* hb) {
        v4f a = *(const v4f*)(base);
        v4f b = *(const v4f*)(base + 4);
        v2f c = *(const v2f*)(base + 8);
        hb[0] = a.x; hb[1] = a.y; hb[2] = a.z; hb[3] = a.w;
        hb[4] = b.x; hb[5] = b.y; hb[6] = b.z; hb[7] = b.w;
        hb[8] = c.x; hb[9] = c.y;
    };

    // ---- state ----
    float c1 = 0.f, c2 = 0.f, h1last = 0.f, h2last = 0.f, yprev = 0.f;
    float h1b[10], h2b[10];
    #pragma unroll
    for (int j = 0; j < HID; ++j) { h1b[j] = 0.f; h2b[j] = 0.f; }

    auto head_ = [&]() -> float {                // verbatim r17
        v2f Y = pfma2(wlp[0], mk2(h2b[0], h2b[1]), mk2(bl, 0.f));
        #pragma unroll
        for (int k = 1; k < 5; ++k)
            Y = pfma2(wlp[k], mk2(h2b[2*k], h2b[2*k + 1]), Y);
        return Y.x + Y.y;
    };

    // W0: cell1 step -> h1 lane value to ring slot
    auto pstep0 = [&](float xt, float* hslot) -> float {
        v2f A_if = dotp(w1_if, h1b, pfma2(wx_if, mk2(xt, xt), b1_if));
        v2f A_go = dotp(w1_go, h1b, pfma2(wx_go, mk2(xt, xt), b1_go));
        float h1n = cellup2(A_if, A_go, c1);
        bcast10(h1n, h1b);
        hslot[lane] = h1n;
        return h1n;
    };
    // W3 future step (full serial cell1+U+cell2+head; values == r17 fstep)
    auto fstep = [&](float yt) -> float {
        v2f A_if = dotp(w1_if, h1b, pfma2(wx_if, mk2(yt, yt), b1_if));
        v2f A_go = dotp(w1_go, h1b, pfma2(wx_go, mk2(yt, yt), b1_go));
        float h1n = cellup2(A_if, A_go, c1);
        bcast10(h1n, h1b);
        v2f U_if = dotp(w2i_if, h1b, b2_if);
        v2f U_go = dotp(w2i_go, h1b, b2_go);
        v2f V_if = dotp(w2h_if, h2b, mk2(U_if.x, U_if.y));
        v2f V_go = dotp(w2h_go, h2b, mk2(U_go.x, U_go.y));
        float h2n = cellup2(V_if, V_go, c2);
        bcast10(h2n, h2b);
        return head_();
    };

    const float4* xrow = (const float4*)(x + (size_t)ge * TMAIN);
    float4* orow = (float4*)(out + (size_t)ge * OUTW);   // OUTW=1088, 16B rows

    float4 z4 = make_float4(0.f, 0.f, 0.f, 0.f);
    float4 xq0 = z4, xq1 = z4, xq2 = z4, xq3 = z4;
    if (wid == 0) { xq0 = xrow[0]; xq1 = xrow[1]; xq2 = xrow[2]; xq3 = xrow[3]; }

    // ---- main pipeline: 67 iterations; W_k processes chunk c-k ----
    #pragma unroll 1
    for (int c = 0; c <= NCH + 2; ++c) {
        if (wid == 0) {
            if (c < NCH) {
                float4 xn0 = z4, xn1 = z4, xn2 = z4, xn3 = z4;
                if (c + 1 < NCH) {
                    xn0 = xrow[(c+1)*4+0]; xn1 = xrow[(c+1)*4+1];
                    xn2 = xrow[(c+1)*4+2]; xn3 = xrow[(c+1)*4+3];
                }
                float* hs = &ringH1[c & 1][0][0];
                h1last = pstep0(xq0.x, hs + 0*64);  h1last = pstep0(xq0.y, hs + 1*64);
                h1last = pstep0(xq0.z, hs + 2*64);  h1last = pstep0(xq0.w, hs + 3*64);
                h1last = pstep0(xq1.x, hs + 4*64);  h1last = pstep0(xq1.y, hs + 5*64);
                h1last = pstep0(xq1.z, hs + 6*64);  h1last = pstep0(xq1.w, hs + 7*64);
                h1last = pstep0(xq2.x, hs + 8*64);  h1last = pstep0(xq2.y, hs + 9*64);
                h1last = pstep0(xq2.z, hs + 10*64); h1last = pstep0(xq2.w, hs + 11*64);
                h1last = pstep0(xq3.x, hs + 12*64); h1last = pstep0(xq3.y, hs + 13*64);
                h1last = pstep0(xq3.z, hs + 14*64); h1last = pstep0(xq3.w, hs + 15*64);
                if (c == NCH - 1) { stC1[lane] = c1; stH1[lane] = h1last; }
                xq0 = xn0; xq1 = xn1; xq2 = xn2; xq3 = xn3;
            }
        } else if (wid == 1) {
            const int cc = c - 1;
            if (cc >= 0 && cc < NCH) {
                const float* hs = &ringH1[cc & 1][0][0];
                v4f* us = &ringU[cc & 1][0][0];
                #pragma unroll
                for (int t = 0; t < KCH; ++t) {
                    float hb[10];
                    loadhb(hs + t*64 + e*16, hb);
                    v2f U_if = dotp(w2i_if, hb, b2_if);
                    v2f U_go = dotp(w2i_go, hb, b2_go);
                    v4f U; U.x = U_if.x; U.y = U_if.y; U.z = U_go.x; U.w = U_go.y;
                    us[t*64 + lane] = U;
                }
            }
        } else if (wid == 2) {
            const int cc = c - 2;
            if (cc >= 0 && cc < NCH) {
                const v4f* us = &ringU[cc & 1][0][0];
                float* h2s = &ringH2[cc & 1][0][0];
                #pragma unroll
                for (int t = 0; t < KCH; ++t) {
                    v4f U = us[t*64 + lane];
                    v2f V_if = dotp(w2h_if, h2b, mk2(U.x, U.y));
                    v2f V_go = dotp(w2h_go, h2b, mk2(U.z, U.w));
                    float h2n = cellup2(V_if, V_go, c2);
                    bcast10(h2n, h2b);
                    h2s[t*64 + lane] = h2n;
                    h2last = h2n;
                }
                if (cc == NCH - 1) { stC2[lane] = c2; stH2[lane] = h2last; }
            }
        } else {
            const int cc = c - 3;
            if (cc >= 0 && cc < NCH) {
                const float* h2s = &ringH2[cc & 1][0][0];
                #pragma unroll
                for (int q = 0; q < 4; ++q) {
                    float y0, y1, y2, y3;
                    loadhb(h2s + (q*4 + 0)*64 + e*16, h2b); y0 = head_();
                    loadhb(h2s + (q*4 + 1)*64 + e*16, h2b); y1 = head_();
                    loadhb(h2s + (q*4 + 2)*64 + e*16, h2b); y2 = head_();
                    loadhb(h2s + (q*4 + 3)*64 + e*16, h2b); y3 = head_();
                    if (u == 0) orow[cc*4 + q] = make_float4(y0, y1, y2, y3);
                    yprev = y3;
                }
            }
        }
        __syncthreads();
    }

    // ---- future loop: W3 only, fully serial (y feeds back) ----
    if (wid == 3) {
        c1 = stC1[lane];
        c2 = stC2[lane];
        loadhb(&stH1[e*16], h1b);
        loadhb(&stH2[e*16], h2b);
        float yp = yprev;
        int t = 0;
        #pragma unroll 1
        for (; t + 3 < F; t += 4) {
            float y0 = fstep(yp);
            float y1 = fstep(y0);
            float y2 = fstep(y1);
            float y3 = fstep(y2);
            if (u == 0) orow[(TMAIN + t) / 4] = make_float4(y0, y1, y2, y3);
            yp = y3;
        }
        #pragma unroll 1
        for (; t < F; ++t) {
            yp = fstep(yp);
            if (u == 0) out[(size_t)ge * OUTW + TMAIN + t] = yp;
        }
    }
}

extern "C" void kernel_launch(void* const* d_in, const int* in_sizes, int n_in,
                              void* d_out, int out_size, void* d_ws, size_t ws_size,
                              hipStream_t stream) {
    const float* x    = (const float*)d_in[0];
    const float* Wih1 = (const float*)d_in[1];
    const float* Whh1 = (const float*)d_in[2];
    const float* bih1 = (const float*)d_in[3];
    const float* bhh1 = (const float*)d_in[4];
    const float* Wih2 = (const float*)d_in[5];
    const float* Whh2 = (const float*)d_in[6];
    const float* bih2 = (const float*)d_in[7];
    const float* bhh2 = (const float*)d_in[8];
    const float* Wlin = (const float*)d_in[9];
    const float* blin = (const float*)d_in[10];
    const int*   futp = (const int*)d_in[11];
    float* out = (float*)d_out;

    lstm2_kernel<<<NB, 256, 0, stream>>>(x, Wih1, Whh1, bih1, bhh1,
                                         Wih2, Whh2, bih2, bhh2,
                                         Wlin, blin, futp, out);
}